// Round 1
// baseline (101.511 us; speedup 1.0000x reference)
//
#include <hip/hip_runtime.h>

// Problem constants (B,K,S1,S2,S3) = (4,8,64,64,64)
#define SB 4
#define SK 8
#define KM1 7                 // k = K-1 channel has R=I, t=0 -> zero contribution
#define NVOX (64 * 64 * 64)
#define NV4 (NVOX / 4)        // 65536 float4 per (b,k) plane
#define NSEG 64               // one x-plane (4096 voxels) per block, per batch
#define NBLK (SB * NSEG)      // 256 blocks == 256 CUs, 1 block/CU -> all co-resident
#define NTHR 1024             // 16 waves/CU
#define GSTEP (2.0f / 63.0f)
#define BAR_FLT_OFF 8192      // barrier word at byte 32768 (past 28 KB of partials)

typedef __attribute__((ext_vector_type(4))) float nt_float4;

// ws layout (floats): partials ws[((b*7+k)*64 + seg)*4 + m], m={S, MX, MY, MZ}
// (28 KB), barrier int at float offset 8192. All cross-block ws traffic uses
// agent-scope atomics (cross-XCD L2s are not coherent).

__global__ __launch_bounds__(NTHR, 4) void fused_motion(
        const float* __restrict__ mask, const float* __restrict__ trans,
        const float* __restrict__ rot, float* __restrict__ out,
        float* __restrict__ ws) {
    const int tid = threadIdx.x;
    const int b   = blockIdx.x >> 6;
    const int seg = blockIdx.x & 63;
    // block covers voxels [seg*4096, (seg+1)*4096): exactly one x-slab -> gx uniform
    const float gx = -1.0f + (float)seg * GSTEP;

    // ---- Phase 1: load this block's slice of 7 k-planes into REGISTERS (once) ----
    const float4* mb = (const float4*)mask + (size_t)b * SK * NV4 + seg * 1024;
    float4 mk[KM1];
#pragma unroll
    for (int k = 0; k < KM1; ++k)
        mk[k] = mb[(size_t)k * NV4 + tid];

    // geometry of this thread's float4 group: v = seg*4096 + tid*4
    const float gy  = -1.0f + (float)(tid >> 4) * GSTEP;
    const float gz0 = -1.0f + (float)((tid & 15) << 2) * GSTEP;
    const float gz1 = gz0 + GSTEP, gz2 = gz0 + 2.f * GSTEP, gz3 = gz0 + 3.f * GSTEP;

    __shared__ float red[NTHR / 64][KM1][3];
    __shared__ float momf[KM1][4];
    __shared__ float cf[KM1 * 12];
    const int wave = tid >> 6, lane = tid & 63;

#pragma unroll
    for (int k = 0; k < KM1; ++k) {
        const float4 m = mk[k];
        const float s4 = m.x + m.y + m.z + m.w;
        float s  = s4;
        float my = gy * s4;
        float mz = fmaf(gz0, m.x, fmaf(gz1, m.y, fmaf(gz2, m.z, gz3 * m.w)));
#pragma unroll
        for (int off = 32; off > 0; off >>= 1) {
            s  += __shfl_down(s,  off, 64);
            my += __shfl_down(my, off, 64);
            mz += __shfl_down(mz, off, 64);
        }
        if (lane == 0) {
            red[wave][k][0] = s; red[wave][k][1] = my; red[wave][k][2] = mz;
        }
    }
    __syncthreads();
    if (tid < KM1 * 4) {
        const int k = tid >> 2, m = tid & 3;
        const int sel = (m <= 1) ? 0 : (m - 1);   // m=0,1 from S; m=2 from MY; m=3 from MZ
        float acc = 0.f;
#pragma unroll
        for (int w = 0; w < NTHR / 64; ++w) acc += red[w][k][sel];
        if (m == 1) acc *= gx;                    // x-moment = gx * S (gx block-uniform)
        float* wp = ws + (((size_t)b * KM1 + k) * NSEG + seg) * 4 + m;
        __hip_atomic_store(wp, acc, __ATOMIC_RELAXED, __HIP_MEMORY_SCOPE_AGENT);
    }
    __syncthreads();   // partial stores ordered before the release RMW below

    // ---- grid barrier: 256 blocks, 1/CU guaranteed by __launch_bounds__ ----
    if (tid == 0) {
        int* bar = (int*)ws + BAR_FLT_OFF;        // memset to 0 each launch/replay
        __hip_atomic_fetch_add(bar, 1, __ATOMIC_ACQ_REL, __HIP_MEMORY_SCOPE_AGENT);
        while (__hip_atomic_load(bar, __ATOMIC_ACQUIRE, __HIP_MEMORY_SCOPE_AGENT) < NBLK)
            __builtin_amdgcn_s_sleep(2);
    }
    __syncthreads();

    // ---- Phase 2a: redundant reduce of the 64 seg-partials for this block's b ----
    if (wave < KM1) {
        const float* wp = ws + (((size_t)b * KM1 + wave) * NSEG + lane) * 4;
        float q0 = __hip_atomic_load(wp + 0, __ATOMIC_RELAXED, __HIP_MEMORY_SCOPE_AGENT);
        float q1 = __hip_atomic_load(wp + 1, __ATOMIC_RELAXED, __HIP_MEMORY_SCOPE_AGENT);
        float q2 = __hip_atomic_load(wp + 2, __ATOMIC_RELAXED, __HIP_MEMORY_SCOPE_AGENT);
        float q3 = __hip_atomic_load(wp + 3, __ATOMIC_RELAXED, __HIP_MEMORY_SCOPE_AGENT);
#pragma unroll
        for (int off = 32; off > 0; off >>= 1) {
            q0 += __shfl_down(q0, off, 64);
            q1 += __shfl_down(q1, off, 64);
            q2 += __shfl_down(q2, off, 64);
            q3 += __shfl_down(q3, off, 64);
        }
        if (lane == 0) {
            momf[wave][0] = q0; momf[wave][1] = q1;
            momf[wave][2] = q2; momf[wave][3] = q3;
        }
    }
    __syncthreads();
    if (tid < KM1) {
        const int k = tid;
        const int base = b * KM1 + k;
        const float S  = momf[k][0];
        const float p0 = momf[k][1] / S;
        const float p1 = momf[k][2] / S;
        const float p2 = momf[k][3] / S;
        const float* R  = rot + base * 9;
        const float* tv = trans + base * 3;
        float* c = cf + k * 12;
        const float c0 = R[0] - 1.0f, c3 = R[3], c6 = R[6];
        c[1] = R[1];        c[2] = R[2];
        c[4] = R[4] - 1.0f; c[5] = R[5];
        c[7] = R[7];        c[8] = R[8] - 1.0f;
        // fold the block-uniform x term into the constant: d = (I-R)p + t + (R-I)_col0 * gx
        c[9]  = fmaf(c0, gx, p0 - (R[0] * p0 + R[1] * p1 + R[2] * p2) + tv[0]);
        c[10] = fmaf(c3, gx, p1 - (R[3] * p0 + R[4] * p1 + R[5] * p2) + tv[1]);
        c[11] = fmaf(c6, gx, p2 - (R[6] * p0 + R[7] * p1 + R[8] * p2) + tv[2]);
    }
    __syncthreads();

    // ---- Phase 2b: output straight from the register-resident mask ----
    float4 o0 = {0, 0, 0, 0}, o1 = {0, 0, 0, 0}, o2 = {0, 0, 0, 0};
#pragma unroll
    for (int k = 0; k < KM1; ++k) {
        const float* c = cf + k * 12;
        const float4 m = mk[k];
        const float tx = fmaf(c[1], gy, c[9]);
        const float ty = fmaf(c[4], gy, c[10]);
        const float tz = fmaf(c[7], gy, c[11]);
        o0.x += m.x * fmaf(c[2], gz0, tx);
        o0.y += m.y * fmaf(c[2], gz1, tx);
        o0.z += m.z * fmaf(c[2], gz2, tx);
        o0.w += m.w * fmaf(c[2], gz3, tx);
        o1.x += m.x * fmaf(c[5], gz0, ty);
        o1.y += m.y * fmaf(c[5], gz1, ty);
        o1.z += m.z * fmaf(c[5], gz2, ty);
        o1.w += m.w * fmaf(c[5], gz3, ty);
        o2.x += m.x * fmaf(c[8], gz0, tz);
        o2.y += m.y * fmaf(c[8], gz1, tz);
        o2.z += m.z * fmaf(c[8], gz2, tz);
        o2.w += m.w * fmaf(c[8], gz3, tz);
    }
    // write-once output: NT stores keep it out of L2/L3
    const size_t ob = (size_t)b * 3 * NV4 + seg * 1024 + tid;
    __builtin_nontemporal_store((nt_float4){o0.x, o0.y, o0.z, o0.w}, (nt_float4*)out + ob);
    __builtin_nontemporal_store((nt_float4){o1.x, o1.y, o1.z, o1.w}, (nt_float4*)out + ob + NV4);
    __builtin_nontemporal_store((nt_float4){o2.x, o2.y, o2.z, o2.w}, (nt_float4*)out + ob + 2 * (size_t)NV4);
}

extern "C" void kernel_launch(void* const* d_in, const int* in_sizes, int n_in,
                              void* d_out, int out_size, void* d_ws, size_t ws_size,
                              hipStream_t stream) {
    const float* mask  = (const float*)d_in[0]; // (4,8,64,64,64)
    const float* trans = (const float*)d_in[1]; // (4,7,3)
    const float* rot   = (const float*)d_in[2]; // (4,7,3,3)
    // barrier word must be zero each launch (ws is poisoned between iterations);
    // memset node re-executes on every graph replay -> replay-safe.
    hipMemsetAsync((char*)d_ws + BAR_FLT_OFF * sizeof(float), 0, 64, stream);
    fused_motion<<<NBLK, NTHR, 0, stream>>>(mask, trans, rot, (float*)d_out, (float*)d_ws);
}

// Round 2
// 86.428 us; speedup vs baseline: 1.1745x; 1.1745x over previous
//
#include <hip/hip_runtime.h>

// Problem constants (B,K,S1,S2,S3) = (4,8,64,64,64)
#define SB 4
#define SK 8
#define KM1 7
#define NBK (SB * KM1)       // 28
#define NVOX (64 * 64 * 64)
#define NV4 (NVOX / 4)       // 65536 float4 per (b,k) plane
#define CHUNKS 32            // partial-reduction blocks per (b,k) (896 blocks)
#define GSTEP (2.0f / 63.0f)

typedef __attribute__((ext_vector_type(4))) float nt_float4;

// ws layout (floats): ws[bk*CHUNKS*4 + chunk*4 + m], m = {S, MX, MY, MZ}
// Written non-atomically by moments_kernel (one block per (bk,chunk));
// reduced redundantly by every output block (its own b only). Kernel-launch
// boundary provides the cross-XCD visibility.
//
// NOTE (session finding, round 1): do NOT add hipMemsetAsync / fill-engine
// nodes to this graph. The harness's per-iteration 2x256MiB poison fills
// (~86.6 us at 6.2 TB/s) dominate dur_us; a fill node serializes our graph
// behind them (+14.5 us measured). Kernel-only graphs overlap the fills.

__global__ __launch_bounds__(256) void moments_kernel(
        const float* __restrict__ mask, float* __restrict__ ws) {
    const int bk = blockIdx.x / CHUNKS;
    const int chunk = blockIdx.x % CHUNKS;
    const int b = bk / KM1;
    const int k = bk % KM1;
    const float4* m4 = (const float4*)(mask + (size_t)(b * SK + k) * NVOX);

    float s = 0.f, mx = 0.f, my = 0.f, mz = 0.f;
    const int base = chunk * (NV4 / CHUNKS) + threadIdx.x;
#pragma unroll
    for (int it = 0; it < (NV4 / CHUNKS) / 256; ++it) {
        const int v4 = base + it * 256;
        const float4 m = m4[v4];
        const int v = v4 << 2;
        const float gx = -1.0f + (float)(v >> 12) * GSTEP;
        const float gy = -1.0f + (float)((v >> 6) & 63) * GSTEP;
        const float gz = -1.0f + (float)(v & 63) * GSTEP;
        const float msum = m.x + m.y + m.z + m.w;
        s  += msum;
        mx += gx * msum;
        my += gy * msum;
        mz += fmaf(gz, m.x, fmaf(gz + GSTEP, m.y,
              fmaf(gz + 2.f * GSTEP, m.z, (gz + 3.f * GSTEP) * m.w)));
    }
    // 64-lane butterfly, then cross-wave via LDS
#pragma unroll
    for (int off = 32; off > 0; off >>= 1) {
        s  += __shfl_down(s,  off, 64);
        mx += __shfl_down(mx, off, 64);
        my += __shfl_down(my, off, 64);
        mz += __shfl_down(mz, off, 64);
    }
    __shared__ float red[4][4];
    const int wave = threadIdx.x >> 6, lane = threadIdx.x & 63;
    if (lane == 0) {
        red[wave][0] = s; red[wave][1] = mx; red[wave][2] = my; red[wave][3] = mz;
    }
    __syncthreads();
    if (threadIdx.x == 0) {
        float a0 = 0.f, a1 = 0.f, a2 = 0.f, a3 = 0.f;
#pragma unroll
        for (int w = 0; w < 4; ++w) {
            a0 += red[w][0]; a1 += red[w][1]; a2 += red[w][2]; a3 += red[w][3];
        }
        float* p = ws + (size_t)bk * (CHUNKS * 4) + chunk * 4;
        p[0] = a0; p[1] = a1; p[2] = a2; p[3] = a3;
    }
}

// out[b,c,v] = sum_k mask[b,k,v] * (M_k g_v + d_k)_c, with per-block
// redundant coefficient construction from the ws partials (L2-broadcast).
__global__ __launch_bounds__(256) void output_kernel(
        const float* __restrict__ mask, const float* __restrict__ ws,
        const float* __restrict__ trans, const float* __restrict__ rot,
        float* __restrict__ out) {
    const int b = blockIdx.y;
    const int tid = threadIdx.x;

    __shared__ float momf[KM1][4];
    __shared__ float cf[KM1 * 12];
    if (tid < KM1 * 4) {
        const int k = tid >> 2, m = tid & 3;
        const float* p = ws + (size_t)(b * KM1 + k) * (CHUNKS * 4) + m;
        float acc = 0.f;
#pragma unroll
        for (int c = 0; c < CHUNKS; ++c) acc += p[c * 4];
        momf[k][m] = acc;
    }
    __syncthreads();
    if (tid < KM1) {
        const int k = tid;
        const int base = b * KM1 + k;
        const float S  = momf[k][0];
        const float p0 = momf[k][1] / S;
        const float p1 = momf[k][2] / S;
        const float p2 = momf[k][3] / S;
        const float* R  = rot + base * 9;
        const float* tv = trans + base * 3;
        float* c = cf + k * 12;
        c[0] = R[0] - 1.0f; c[1] = R[1];        c[2] = R[2];
        c[3] = R[3];        c[4] = R[4] - 1.0f; c[5] = R[5];
        c[6] = R[6];        c[7] = R[7];        c[8] = R[8] - 1.0f;
        c[9]  = p0 - (R[0] * p0 + R[1] * p1 + R[2] * p2) + tv[0];
        c[10] = p1 - (R[3] * p0 + R[4] * p1 + R[5] * p2) + tv[1];
        c[11] = p2 - (R[6] * p0 + R[7] * p1 + R[8] * p2) + tv[2];
    }
    __syncthreads();

    const int v4 = blockIdx.x * 256 + tid;
    const int v = v4 << 2;
    const float gx  = -1.0f + (float)(v >> 12) * GSTEP;
    const float gy  = -1.0f + (float)((v >> 6) & 63) * GSTEP;
    const float gz0 = -1.0f + (float)(v & 63) * GSTEP;
    const float gz1 = gz0 + GSTEP, gz2 = gz0 + 2.f * GSTEP, gz3 = gz0 + 3.f * GSTEP;

    float4 o0 = {0, 0, 0, 0}, o1 = {0, 0, 0, 0}, o2 = {0, 0, 0, 0};
    const float4* m4 = (const float4*)mask + (size_t)b * SK * NV4 + v4;
#pragma unroll
    for (int k = 0; k < KM1; ++k) {
        const float4 m = m4[(size_t)k * NV4];
        const float* c = cf + k * 12;
        const float tx = fmaf(c[0], gx, fmaf(c[1], gy, c[9]));
        const float ty = fmaf(c[3], gx, fmaf(c[4], gy, c[10]));
        const float tz = fmaf(c[6], gx, fmaf(c[7], gy, c[11]));
        o0.x += m.x * fmaf(c[2], gz0, tx);
        o0.y += m.y * fmaf(c[2], gz1, tx);
        o0.z += m.z * fmaf(c[2], gz2, tx);
        o0.w += m.w * fmaf(c[2], gz3, tx);
        o1.x += m.x * fmaf(c[5], gz0, ty);
        o1.y += m.y * fmaf(c[5], gz1, ty);
        o1.z += m.z * fmaf(c[5], gz2, ty);
        o1.w += m.w * fmaf(c[5], gz3, ty);
        o2.x += m.x * fmaf(c[8], gz0, tz);
        o2.y += m.y * fmaf(c[8], gz1, tz);
        o2.z += m.z * fmaf(c[8], gz2, tz);
        o2.w += m.w * fmaf(c[8], gz3, tz);
    }
    // Output is write-once/never-read in this dispatch chain: nontemporal
    // stores keep the L2/L3-warm mask lines from being evicted mid-kernel.
    // (builtin needs a native clang vector type, not HIP_vector_type)
    nt_float4* q0 = (nt_float4*)out + ((size_t)b * 3 + 0) * NV4 + v4;
    nt_float4* q1 = (nt_float4*)out + ((size_t)b * 3 + 1) * NV4 + v4;
    nt_float4* q2 = (nt_float4*)out + ((size_t)b * 3 + 2) * NV4 + v4;
    __builtin_nontemporal_store((nt_float4){o0.x, o0.y, o0.z, o0.w}, q0);
    __builtin_nontemporal_store((nt_float4){o1.x, o1.y, o1.z, o1.w}, q1);
    __builtin_nontemporal_store((nt_float4){o2.x, o2.y, o2.z, o2.w}, q2);
}

extern "C" void kernel_launch(void* const* d_in, const int* in_sizes, int n_in,
                              void* d_out, int out_size, void* d_ws, size_t ws_size,
                              hipStream_t stream) {
    const float* mask  = (const float*)d_in[0]; // (4,8,64,64,64)
    const float* trans = (const float*)d_in[1]; // (4,7,3)
    const float* rot   = (const float*)d_in[2]; // (4,7,3,3)
    float* out = (float*)d_out;                 // (4,3,64,64,64)
    float* ws  = (float*)d_ws;                  // 28*CHUNKS*4 floats of partials

    moments_kernel<<<NBK * CHUNKS, 256, 0, stream>>>(mask, ws);
    output_kernel<<<dim3(NV4 / 256, SB), 256, 0, stream>>>(mask, ws, trans, rot, out);
}